// Round 1
// baseline (140.215 us; speedup 1.0000x reference)
//
#include <hip/hip_runtime.h>

// FineMatching: per-proposal row/col top-3 sparsification + masked fusion.
// P=512 proposals, R=S=128. Outputs: score_map [P,R,S] f32, corr_map [P,R,S] bool(as f32),
// concatenated flat in d_out.

constexpr int NP = 512;
constexpr int NR = 128;
constexpr int NS = 128;
constexpr int RS = NR * NS;          // 16384
constexpr float THRESHOLD = 0.05f;

__device__ __forceinline__ void top3_insert(float v, float& m0, float& m1, float& m2) {
    if (v > m2) {
        if (v > m0)      { m2 = m1; m1 = m0; m0 = v; }
        else if (v > m1) { m2 = m1; m1 = v; }
        else             { m2 = v; }
    }
}

__global__ __launch_bounds__(256) void fine_matching_kernel(
    const float* __restrict__ in,     // [P,R,S] raw log-scores
    const int*   __restrict__ rmask,  // [P,R]   0/1
    const int*   __restrict__ smask,  // [P,S]   0/1
    const float* __restrict__ ncs,    // [P]
    float*       __restrict__ out)    // [2,P,R,S]: score_map then corr_map
{
    __shared__ float tile[RS];        // 64 KB exactly: raw scores, stride 128 (no pad;
                                      // row scan uses rotated index to dodge bank conflicts)
    const int p = blockIdx.x;
    const int t = threadIdx.x;

    const float*  base      = in  + (size_t)p * RS;
    float*        score_out = out + (size_t)p * RS;
    float*        corr_out  = out + (size_t)(NP + p) * RS;  // also used as threshold stash

    // ---- Phase 1: load tile (coalesced float4) ----
    const float4* b4 = (const float4*)base;
    float4*       t4 = (float4*)tile;
    #pragma unroll
    for (int k = 0; k < 16; ++k) {
        int i4 = t + k * 256;         // 4096 float4s total
        t4[i4] = b4[i4];
    }
    __syncthreads();

    // ---- Phase 2: top-3 thresholds on raw scores (exp is monotonic) ----
    // waves 0-1: one row each; waves 2-3: one column each. Wave-uniform branch.
    if (t < 128) {
        float m0 = -3.4e38f, m1 = -3.4e38f, m2 = -3.4e38f;
        const float* row = &tile[t * NS];
        #pragma unroll 4
        for (int c = 0; c < NS; ++c) {
            float v = row[(c + t) & 127];     // rotation: bank = (c+t)%32, conflict-free
            top3_insert(v, m0, m1, m2);
        }
        corr_out[t] = m2;                     // stash t_row[t] (overwritten in phase 4)
    } else {
        const int j = t - 128;
        float m0 = -3.4e38f, m1 = -3.4e38f, m2 = -3.4e38f;
        #pragma unroll 4
        for (int r = 0; r < NR; ++r) {
            float v = tile[r * NS + j];       // lanes consecutive: conflict-free
            top3_insert(v, m0, m1, m2);
        }
        corr_out[128 + j] = m2;               // stash t_col[j]
    }
    __syncthreads();  // global writes visible block-wide after barrier

    // ---- Phase 3: preload per-thread thresholds/masks into registers ----
    const float ncs_p = ncs[p];
    const int   s0    = (t & 31) << 2;        // this thread's 4 columns (constant over k)
    const float4 tc   = *(const float4*)&corr_out[128 + s0];
    const int4   ms   = *(const int4*)&smask[p * NS + s0];
    float trow[16];
    int   mrow[16];
    #pragma unroll
    for (int k = 0; k < 16; ++k) {
        int r = (t >> 5) + 8 * k;             // this thread's row at iteration k
        trow[k] = corr_out[r];
        mrow[k] = rmask[p * NR + r];
    }
    __syncthreads();  // everyone done reading the stash before we overwrite it

    // ---- Phase 4: elementwise epilogue ----
    float4* sc4 = (float4*)score_out;
    float4* co4 = (float4*)corr_out;
    #pragma unroll
    for (int k = 0; k < 16; ++k) {
        int i4 = t + k * 256;
        float4 x = t4[i4];                    // contiguous 1KB/wave: conflict-free b128
        float tr = trow[k];
        bool  mr = (mrow[k] != 0);
        float4 sc, co;

        {   float m  = __expf(x.x);
            float rs = (x.x >= tr)   ? m : 0.f;
            float cs = (x.x >= tc.x) ? m : 0.f;
            sc.x = 0.5f * (rs + cs) * ncs_p;
            co.x = (mr && (ms.x != 0) && (rs > THRESHOLD || cs > THRESHOLD)) ? 1.f : 0.f; }
        {   float m  = __expf(x.y);
            float rs = (x.y >= tr)   ? m : 0.f;
            float cs = (x.y >= tc.y) ? m : 0.f;
            sc.y = 0.5f * (rs + cs) * ncs_p;
            co.y = (mr && (ms.y != 0) && (rs > THRESHOLD || cs > THRESHOLD)) ? 1.f : 0.f; }
        {   float m  = __expf(x.z);
            float rs = (x.z >= tr)   ? m : 0.f;
            float cs = (x.z >= tc.z) ? m : 0.f;
            sc.z = 0.5f * (rs + cs) * ncs_p;
            co.z = (mr && (ms.z != 0) && (rs > THRESHOLD || cs > THRESHOLD)) ? 1.f : 0.f; }
        {   float m  = __expf(x.w);
            float rs = (x.w >= tr)   ? m : 0.f;
            float cs = (x.w >= tc.w) ? m : 0.f;
            sc.w = 0.5f * (rs + cs) * ncs_p;
            co.w = (mr && (ms.w != 0) && (rs > THRESHOLD || cs > THRESHOLD)) ? 1.f : 0.f; }

        sc4[i4] = sc;
        co4[i4] = co;
    }
}

extern "C" void kernel_launch(void* const* d_in, const int* in_sizes, int n_in,
                              void* d_out, int out_size, void* d_ws, size_t ws_size,
                              hipStream_t stream) {
    const float* msm   = (const float*)d_in[0];  // [P,R,S] f32
    const int*   rmask = (const int*)  d_in[1];  // [P,R] bool->int
    const int*   smask = (const int*)  d_in[2];  // [P,S] bool->int
    const float* ncs   = (const float*)d_in[3];  // [P] f32
    float* out = (float*)d_out;

    fine_matching_kernel<<<NP, 256, 0, stream>>>(msm, rmask, smask, ncs, out);
}

// Round 2
// 110.069 us; speedup vs baseline: 1.2739x; 1.2739x over previous
//
#include <hip/hip_runtime.h>

// FineMatching, two-kernel version:
//  K1 thresholds: per-proposal row/col 3rd-largest raw score -> d_ws
//  K2 epilogue:   streaming elementwise score/corr computation
// P=512, R=S=128. d_out = [score_map (P*R*S), corr_map (P*R*S)] f32.
// d_ws layout: per proposal p, 256 floats: [0:128)=t_col[j], [128:256)=t_row[r].

constexpr int NP = 512;
constexpr int NR = 128;
constexpr int NS = 128;
constexpr int RS = NR * NS;          // 16384
constexpr float THRESHOLD = 0.05f;
constexpr float NEG_INF = -3.4e38f;

__device__ __forceinline__ void top3_insert(float v, float& m0, float& m1, float& m2) {
    // branchless-ish: compiler lowers to cndmask chains
    bool g2 = v > m2, g1 = v > m1, g0 = v > m0;
    float n2 = g1 ? m1 : (g2 ? v : m2);
    float n1 = g0 ? m0 : (g1 ? v : m1);
    float n0 = g0 ? v : m0;
    m0 = n0; m1 = n1; m2 = n2;
}

// 3rd largest of union of two descending triples (a0>=a1>=a2, b0>=b1>=b2)
__device__ __forceinline__ float third_of_merge(float a0, float a1, float a2,
                                                float b0, float b1, float b2) {
    float third = NEG_INF;
    #pragma unroll
    for (int k = 0; k < 3; ++k) {
        bool ta = a0 >= b0;
        third = ta ? a0 : b0;
        float na0 = ta ? a1 : a0, na1 = ta ? a2 : a1;
        float nb0 = ta ? b0 : b1, nb1 = ta ? b1 : b2;
        a0 = na0; a1 = na1; a2 = ta ? NEG_INF : a2;
        b0 = nb0; b1 = nb1; b2 = ta ? b2 : NEG_INF;
    }
    return third;
}

// grid = 2*NP blocks; even block b=2p: column thresholds, odd b=2p+1: row thresholds
__global__ __launch_bounds__(256) void thresholds_kernel(
    const float* __restrict__ in, float* __restrict__ ws)
{
    const int b = blockIdx.x;
    const int p = b >> 1;
    const int t = threadIdx.x;
    const float* base = in + (size_t)p * RS;
    __shared__ float mbuf[NS * 3];

    if (b & 1) {
        // rows: thread t -> row t>>1, half t&1 (lanes 2r,2r+1 in same wave)
        const int row = t >> 1, half = t & 1;
        const float4* r4 = (const float4*)(base + row * NS + half * 64);
        float m0 = NEG_INF, m1 = NEG_INF, m2 = NEG_INF;
        #pragma unroll
        for (int k = 0; k < 16; ++k) {
            float4 v = r4[k];
            top3_insert(v.x, m0, m1, m2);
            top3_insert(v.y, m0, m1, m2);
            top3_insert(v.z, m0, m1, m2);
            top3_insert(v.w, m0, m1, m2);
        }
        float o0 = __shfl_xor(m0, 1);
        float o1 = __shfl_xor(m1, 1);
        float o2 = __shfl_xor(m2, 1);
        float third = third_of_merge(m0, m1, m2, o0, o1, o2);
        if (half == 0) ws[p * 256 + 128 + row] = third;
    } else {
        // cols: thread t -> col t&127, row-half t>>7 (64 rows each), coalesced b32
        const int col = t & 127, rh = t >> 7;
        const float* c0 = base + (size_t)(rh * 64) * NS + col;
        float m0 = NEG_INF, m1 = NEG_INF, m2 = NEG_INF;
        #pragma unroll 16
        for (int r = 0; r < 64; ++r)
            top3_insert(c0[r * NS], m0, m1, m2);
        if (rh) {
            mbuf[col * 3 + 0] = m0; mbuf[col * 3 + 1] = m1; mbuf[col * 3 + 2] = m2;
        }
        __syncthreads();
        if (!rh) {
            float third = third_of_merge(m0, m1, m2,
                                         mbuf[col * 3], mbuf[col * 3 + 1], mbuf[col * 3 + 2]);
            ws[p * 256 + col] = third;
        }
    }
}

// grid = NP*RS/4/256 = 8192 blocks; one float4 chunk per thread
__global__ __launch_bounds__(256) void epilogue_kernel(
    const float* __restrict__ in,
    const int*   __restrict__ rmask,
    const int*   __restrict__ smask,
    const float* __restrict__ ncs,
    const float* __restrict__ ws,
    float*       __restrict__ out)
{
    const int gid = blockIdx.x * 256 + threadIdx.x;   // chunk index, [0, 2097152)
    const int p   = gid >> 12;                         // 4096 chunks per proposal
    const int rem = gid & 4095;
    const int r   = rem >> 5;                          // 32 chunks per row
    const int c4  = rem & 31;

    const float4 x   = ((const float4*)in)[gid];
    const float  tr  = ws[p * 256 + 128 + r];
    const float4 tc  = ((const float4*)(ws + p * 256))[c4];
    const bool   mr  = rmask[p * NR + r] != 0;
    const int4   ms  = ((const int4*)(smask + (size_t)p * NS))[c4];
    const float  nc  = ncs[p];

    float4 sc, co;
    {   float m  = __expf(x.x);
        float rs = (x.x >= tr)   ? m : 0.f;
        float cs = (x.x >= tc.x) ? m : 0.f;
        sc.x = 0.5f * (rs + cs) * nc;
        co.x = (mr && (ms.x != 0) && (rs > THRESHOLD || cs > THRESHOLD)) ? 1.f : 0.f; }
    {   float m  = __expf(x.y);
        float rs = (x.y >= tr)   ? m : 0.f;
        float cs = (x.y >= tc.y) ? m : 0.f;
        sc.y = 0.5f * (rs + cs) * nc;
        co.y = (mr && (ms.y != 0) && (rs > THRESHOLD || cs > THRESHOLD)) ? 1.f : 0.f; }
    {   float m  = __expf(x.z);
        float rs = (x.z >= tr)   ? m : 0.f;
        float cs = (x.z >= tc.z) ? m : 0.f;
        sc.z = 0.5f * (rs + cs) * nc;
        co.z = (mr && (ms.z != 0) && (rs > THRESHOLD || cs > THRESHOLD)) ? 1.f : 0.f; }
    {   float m  = __expf(x.w);
        float rs = (x.w >= tr)   ? m : 0.f;
        float cs = (x.w >= tc.w) ? m : 0.f;
        sc.w = 0.5f * (rs + cs) * nc;
        co.w = (mr && (ms.w != 0) && (rs > THRESHOLD || cs > THRESHOLD)) ? 1.f : 0.f; }

    ((float4*)out)[gid] = sc;                          // score_map
    ((float4*)(out + (size_t)NP * RS))[gid] = co;      // corr_map
}

extern "C" void kernel_launch(void* const* d_in, const int* in_sizes, int n_in,
                              void* d_out, int out_size, void* d_ws, size_t ws_size,
                              hipStream_t stream) {
    const float* msm   = (const float*)d_in[0];  // [P,R,S] f32
    const int*   rmask = (const int*)  d_in[1];  // [P,R]
    const int*   smask = (const int*)  d_in[2];  // [P,S]
    const float* ncs   = (const float*)d_in[3];  // [P]
    float* out = (float*)d_out;
    float* ws  = (float*)d_ws;                   // needs 512*256*4 = 512 KB

    thresholds_kernel<<<2 * NP, 256, 0, stream>>>(msm, ws);
    epilogue_kernel<<<NP * RS / 4 / 256, 256, 0, stream>>>(msm, rmask, smask, ncs, ws, out);
}

// Round 3
// 98.162 us; speedup vs baseline: 1.4284x; 1.1213x over previous
//
#include <hip/hip_runtime.h>

// FineMatching, fused single-kernel version.
// One block per proposal (512 blocks x 512 threads), 64 KB LDS tile.
// Phases: global->LDS load | row top-3 + col top-3 (raw scores; exp is
// monotonic) stashed via d_ws (L2 round-trip, block-visible after barrier —
// pattern validated in R1) | elementwise epilogue from LDS.
// d_out = [score_map (P*R*S), corr_map (P*R*S)] f32.
// d_ws: per proposal 256 floats: [0:128)=row thirds, [128:256)=col thirds.

constexpr int NP = 512;
constexpr int NR = 128;
constexpr int NS = 128;
constexpr int RS = NR * NS;          // 16384 floats = 64 KB
constexpr float THRESHOLD = 0.05f;
constexpr float NEG_INF = -3.4e38f;

__device__ __forceinline__ void top3_insert(float v, float& m0, float& m1, float& m2) {
    // branchless: lowers to v_cmp + v_cndmask chains, no exec-mask churn
    bool g2 = v > m2, g1 = v > m1, g0 = v > m0;
    float n2 = g1 ? m1 : (g2 ? v : m2);
    float n1 = g0 ? m0 : (g1 ? v : m1);
    float n0 = g0 ? v : m0;
    m0 = n0; m1 = n1; m2 = n2;
}

__device__ __forceinline__ void shfl_merge3(int d, float& m0, float& m1, float& m2) {
    float o0 = __shfl_xor(m0, d);
    float o1 = __shfl_xor(m1, d);
    float o2 = __shfl_xor(m2, d);
    top3_insert(o0, m0, m1, m2);
    top3_insert(o1, m0, m1, m2);
    top3_insert(o2, m0, m1, m2);
}

__global__ __launch_bounds__(512, 4) void fused_kernel(
    const float* __restrict__ in,     // [P,R,S] raw log-scores
    const int*   __restrict__ rmask,  // [P,R]
    const int*   __restrict__ smask,  // [P,S]
    const float* __restrict__ ncs,    // [P]
    float*       __restrict__ ws,     // [P,256] threshold stash
    float*       __restrict__ out)    // [2,P,R,S]
{
    __shared__ float tile[RS];        // 64 KB exactly
    const int p = blockIdx.x;
    const int t = threadIdx.x;

    const float4* b4 = (const float4*)(in + (size_t)p * RS);
    float4*       t4 = (float4*)tile;

    // ---- Phase 1: load tile (coalesced float4, linear -> conflict-free LDS writes)
    #pragma unroll
    for (int k = 0; k < 8; ++k) {
        int i4 = t + k * 512;
        t4[i4] = b4[i4];
    }
    __syncthreads();

    float* ws_row = ws + (size_t)p * 256;
    float* ws_col = ws_row + 128;

    // ---- Phase 2a: row thirds. thread -> (row t>>2, quarter t&3), 32 floats each.
    // float4 reads with (j+t)&7 rotation: 8 bank-groups x 8 lanes = full throughput.
    {
        const int row = t >> 2, q = t & 3;
        const int base4 = row * 32 + q * 8;       // float4 units
        float m0 = NEG_INF, m1 = NEG_INF, m2 = NEG_INF;
        #pragma unroll
        for (int j = 0; j < 8; ++j) {
            int jj = (j + t) & 7;
            float4 v = t4[base4 + jj];
            top3_insert(v.x, m0, m1, m2);
            top3_insert(v.y, m0, m1, m2);
            top3_insert(v.z, m0, m1, m2);
            top3_insert(v.w, m0, m1, m2);
        }
        shfl_merge3(1, m0, m1, m2);               // merge quarters (in-wave lanes)
        shfl_merge3(2, m0, m1, m2);
        if (q == 0) ws_row[row] = m2;
    }

    // ---- Phase 2b: col thirds. thread -> (col t>>2, seg t&3), 32 rows each.
    // b32 reads, 4-way bank conflict (16 cols/wave) — ~1.58x on a short scan, accepted.
    {
        const int col = t >> 2, seg = t & 3;
        float m0 = NEG_INF, m1 = NEG_INF, m2 = NEG_INF;
        #pragma unroll 8
        for (int i = 0; i < 32; ++i) {
            float v = tile[(seg * 32 + i) * NS + col];
            top3_insert(v, m0, m1, m2);
        }
        shfl_merge3(1, m0, m1, m2);
        shfl_merge3(2, m0, m1, m2);
        if (seg == 0) ws_col[col] = m2;
    }

    __threadfence_block();
    __syncthreads();   // stash visible block-wide (R1-proven pattern)

    // ---- Phase 3: epilogue. thread t -> chunks t + k*512 (linear, conflict-free b128).
    // col4 index = (t+k*512)&31 = t&31 (constant); row = (t>>5) + k*16.
    const float  nc = ncs[p];
    const float4 tc = ((const float4*)ws_col)[t & 31];
    const int4   ms = ((const int4*)(smask + (size_t)p * NS))[t & 31];
    float trow[8];
    int   mrow[8];
    #pragma unroll
    for (int k = 0; k < 8; ++k) {
        int row = (t >> 5) + k * 16;
        trow[k] = ws_row[row];                    // L2 hit, 2 addrs/wave -> broadcast
        mrow[k] = rmask[p * NR + row];
    }

    float4* sc4 = (float4*)(out + (size_t)p * RS);
    float4* co4 = (float4*)(out + (size_t)(NP + p) * RS);
    #pragma unroll
    for (int k = 0; k < 8; ++k) {
        int C = t + k * 512;
        float4 x = t4[C];
        float tr = trow[k];
        bool  mr = mrow[k] != 0;
        float4 sc, co;

        {   float m  = __expf(x.x);
            float rs = (x.x >= tr)   ? m : 0.f;
            float cs = (x.x >= tc.x) ? m : 0.f;
            sc.x = 0.5f * (rs + cs) * nc;
            co.x = (mr && (ms.x != 0) && (rs > THRESHOLD || cs > THRESHOLD)) ? 1.f : 0.f; }
        {   float m  = __expf(x.y);
            float rs = (x.y >= tr)   ? m : 0.f;
            float cs = (x.y >= tc.y) ? m : 0.f;
            sc.y = 0.5f * (rs + cs) * nc;
            co.y = (mr && (ms.y != 0) && (rs > THRESHOLD || cs > THRESHOLD)) ? 1.f : 0.f; }
        {   float m  = __expf(x.z);
            float rs = (x.z >= tr)   ? m : 0.f;
            float cs = (x.z >= tc.z) ? m : 0.f;
            sc.z = 0.5f * (rs + cs) * nc;
            co.z = (mr && (ms.z != 0) && (rs > THRESHOLD || cs > THRESHOLD)) ? 1.f : 0.f; }
        {   float m  = __expf(x.w);
            float rs = (x.w >= tr)   ? m : 0.f;
            float cs = (x.w >= tc.w) ? m : 0.f;
            sc.w = 0.5f * (rs + cs) * nc;
            co.w = (mr && (ms.w != 0) && (rs > THRESHOLD || cs > THRESHOLD)) ? 1.f : 0.f; }

        sc4[C] = sc;
        co4[C] = co;
    }
}

extern "C" void kernel_launch(void* const* d_in, const int* in_sizes, int n_in,
                              void* d_out, int out_size, void* d_ws, size_t ws_size,
                              hipStream_t stream) {
    const float* msm   = (const float*)d_in[0];  // [P,R,S] f32
    const int*   rmask = (const int*)  d_in[1];  // [P,R]
    const int*   smask = (const int*)  d_in[2];  // [P,S]
    const float* ncs   = (const float*)d_in[3];  // [P]
    float* out = (float*)d_out;
    float* ws  = (float*)d_ws;                   // uses 512*256*4 = 512 KB

    fused_kernel<<<NP, 512, 0, stream>>>(msm, rmask, smask, ncs, ws, out);
}

// Round 4
// 98.129 us; speedup vs baseline: 1.4289x; 1.0003x over previous
//
#include <hip/hip_runtime.h>

// FineMatching fused v2. One block per proposal (512 x 512 threads), 64 KB
// XOR-swizzled LDS tile (slot = row*32 + (c4 ^ (row&31)) in float4 units).
// Row top-3 is fused into the global load (computed on registers, merged
// in-wave via shfl_xor over the quarter-group, consumed by the SAME thread
// in the epilogue -> zero communication). Col top-3 scans the swizzled tile
// with interleaved row order (r = 4*seg + (i&3) + 16*(i>>2)) -> 2-way bank
// aliasing only (free). Col thresholds cross waves -> d_ws stash + fence +
// sync (pattern validated R1/R3).
// d_out = [score_map (P*R*S), corr_map (P*R*S)] f32.
// d_ws: per proposal 128 floats: col thirds.

constexpr int NP = 512;
constexpr int NR = 128;
constexpr int NS = 128;
constexpr int RS = NR * NS;          // 16384 floats = 64 KB
constexpr float THRESHOLD = 0.05f;
constexpr float NEG_INF = -3.4e38f;

__device__ __forceinline__ void top3_insert(float v, float& m0, float& m1, float& m2) {
    // branchless: v_cmp + v_cndmask chains
    bool g2 = v > m2, g1 = v > m1, g0 = v > m0;
    float n2 = g1 ? m1 : (g2 ? v : m2);
    float n1 = g0 ? m0 : (g1 ? v : m1);
    float n0 = g0 ? v : m0;
    m0 = n0; m1 = n1; m2 = n2;
}

__device__ __forceinline__ void shfl_merge3(int d, float& m0, float& m1, float& m2) {
    float o0 = __shfl_xor(m0, d);
    float o1 = __shfl_xor(m1, d);
    float o2 = __shfl_xor(m2, d);
    top3_insert(o0, m0, m1, m2);
    top3_insert(o1, m0, m1, m2);
    top3_insert(o2, m0, m1, m2);
}

__global__ __launch_bounds__(512, 4) void fused_kernel(
    const float* __restrict__ in,     // [P,R,S] raw log-scores
    const int*   __restrict__ rmask,  // [P,R]
    const int*   __restrict__ smask,  // [P,S]
    const float* __restrict__ ncs,    // [P]
    float*       __restrict__ ws,     // [P,128] col-third stash
    float*       __restrict__ out)    // [2,P,R,S]
{
    __shared__ float4 tile4[RS / 4];  // 64 KB exactly, XOR-swizzled by row
    const int p   = blockIdx.x;
    const int t   = threadIdx.x;
    const int row = t >> 2;           // this thread's row (load + epilogue)
    const int q   = t & 3;            // quarter within row

    const float4* b4 = (const float4*)(in + (size_t)p * RS);
    float* ws_col = ws + (size_t)p * 128;

    // ---- Phase 1: load (coalesced: 16 rows x 64B per instr) + row top-3 on
    //      registers + swizzled LDS store (8 lanes/bank-group: conflict-free).
    float r0 = NEG_INF, r1 = NEG_INF, r2 = NEG_INF;
    #pragma unroll
    for (int j = 0; j < 8; ++j) {
        int c4 = q + 4 * j;
        float4 v = b4[row * 32 + c4];
        tile4[row * 32 + (c4 ^ (row & 31))] = v;
        top3_insert(v.x, r0, r1, r2);
        top3_insert(v.y, r0, r1, r2);
        top3_insert(v.z, r0, r1, r2);
        top3_insert(v.w, r0, r1, r2);
    }
    shfl_merge3(1, r0, r1, r2);       // merge quarter-group (lanes 4r..4r+3)
    shfl_merge3(2, r0, r1, r2);
    const float tr = r2;              // third-largest of row `row` — stays here
    __syncthreads();

    // ---- Phase 2: col top-3 from swizzled tile. col = t>>2, seg = t&3,
    //      rows r = 4*seg + (i&3) + 16*(i>>2): bank = 4*((c4c^r)&7)+(col&3)
    //      picks up seg parity in bit2 -> 2-way aliasing only (free).
    {
        const int col = t >> 2, seg = t & 3;
        const int c4c = col >> 2, cw = col & 3;
        const float* tf = (const float*)tile4;
        float c0 = NEG_INF, c1 = NEG_INF, c2 = NEG_INF;
        #pragma unroll 8
        for (int i = 0; i < 32; ++i) {
            int r = 4 * seg + (i & 3) + 16 * (i >> 2);
            float v = tf[r * 128 + ((c4c ^ (r & 31)) << 2) + cw];
            top3_insert(v, c0, c1, c2);
        }
        shfl_merge3(1, c0, c1, c2);   // merge segs (lanes 4c..4c+3)
        shfl_merge3(2, c0, c1, c2);
        if (seg == 0) ws_col[col] = c2;
    }
    __threadfence_block();
    __syncthreads();                  // ws_col visible block-wide (proven pattern)

    // ---- Phase 3: epilogue. Same chunks as phase 1 (coalesced stores,
    //      conflict-free swizzled LDS re-reads). tr already in-register.
    const float nc = ncs[p];
    const bool  mr = rmask[p * NR + row] != 0;
    float4* sc4 = (float4*)(out + (size_t)p * RS);
    float4* co4 = (float4*)(out + (size_t)(NP + p) * RS);
    const float4* wc4 = (const float4*)ws_col;
    const int4*   sm4 = (const int4*)(smask + (size_t)p * NS);

    #pragma unroll
    for (int j = 0; j < 8; ++j) {
        int c4 = q + 4 * j;
        float4 x  = tile4[row * 32 + (c4 ^ (row & 31))];
        float4 tc = wc4[c4];          // mostly wave-broadcast (4 addrs/wave), L2-hot
        int4   ms = sm4[c4];
        float4 sc, co;

        {   float m  = __expf(x.x);
            float rs = (x.x >= tr)   ? m : 0.f;
            float cs = (x.x >= tc.x) ? m : 0.f;
            sc.x = 0.5f * (rs + cs) * nc;
            co.x = (mr && (ms.x != 0) && (rs > THRESHOLD || cs > THRESHOLD)) ? 1.f : 0.f; }
        {   float m  = __expf(x.y);
            float rs = (x.y >= tr)   ? m : 0.f;
            float cs = (x.y >= tc.y) ? m : 0.f;
            sc.y = 0.5f * (rs + cs) * nc;
            co.y = (mr && (ms.y != 0) && (rs > THRESHOLD || cs > THRESHOLD)) ? 1.f : 0.f; }
        {   float m  = __expf(x.z);
            float rs = (x.z >= tr)   ? m : 0.f;
            float cs = (x.z >= tc.z) ? m : 0.f;
            sc.z = 0.5f * (rs + cs) * nc;
            co.z = (mr && (ms.z != 0) && (rs > THRESHOLD || cs > THRESHOLD)) ? 1.f : 0.f; }
        {   float m  = __expf(x.w);
            float rs = (x.w >= tr)   ? m : 0.f;
            float cs = (x.w >= tc.w) ? m : 0.f;
            sc.w = 0.5f * (rs + cs) * nc;
            co.w = (mr && (ms.w != 0) && (rs > THRESHOLD || cs > THRESHOLD)) ? 1.f : 0.f; }

        sc4[row * 32 + c4] = sc;
        co4[row * 32 + c4] = co;
    }
}

extern "C" void kernel_launch(void* const* d_in, const int* in_sizes, int n_in,
                              void* d_out, int out_size, void* d_ws, size_t ws_size,
                              hipStream_t stream) {
    const float* msm   = (const float*)d_in[0];  // [P,R,S] f32
    const int*   rmask = (const int*)  d_in[1];  // [P,R]
    const int*   smask = (const int*)  d_in[2];  // [P,S]
    const float* ncs   = (const float*)d_in[3];  // [P]
    float* out = (float*)d_out;
    float* ws  = (float*)d_ws;                   // uses 512*128*4 = 256 KB

    fused_kernel<<<NP, 512, 0, stream>>>(msm, rmask, smask, ncs, ws, out);
}